// Round 1
// 266.615 us; speedup vs baseline: 1.0338x; 1.0338x over previous
//
#include <hip/hip_runtime.h>
#include <hip/hip_bf16.h>
#include <math.h>

// Mixer2dTriU: B=64, T=512, C=512, fp32 in/out.
// Pipeline:
//   memset(red)                             -- zero stat accumulators
//   conv_weights: tril(M), W1, W2 -> bf16
//   ln_stats:     per-batch sum/sumsq of inputs (split-16, atomicAdd)
//   ln1_norm_t:   normalize + affine, write XnT[b][c][t] bf16 (LDS transpose)
//   gemm_mixer:   Z = tril(M)@Xn + tri_b + inputs (bf16 MFMA, tril k-skip),
//                 fused ln2 partial stats via atomicAdd
//   ln2_norm:     X2 = ln2(Z) bf16
//   gemm_d1:      H = gelu(X2@W1^T + b1) bf16
//   gemm_d2:      out = X2 + H@W2^T + b2  (fp32)
//
// GEMM mainloop: T3 minimum-2-phase double-buffered LDS (prefetch tile kt+1
// before computing tile kt; single __syncthreads per tile so the vmcnt(0)
// drain lands AFTER compute), plus XOR-swizzled LDS chunks (swizzle applied
// on the per-lane GLOBAL source + same XOR on the ds_read side; LDS dest of
// global_load_lds stays linear per rule #21). XCD-aware block swizzle for
// A-strip L2 reuse (nwg=1024, divisible by 8 -> simple bijective form).

#define B_ 64
#define T_ 512
#define C_ 512
#define TC_ (T_ * C_)
static_assert(TC_ == 262144, "");

typedef __attribute__((ext_vector_type(8))) short bf16x8;
typedef __attribute__((ext_vector_type(4))) float f32x4;

__device__ __forceinline__ unsigned short f2bf(float f) {
  union { float f; unsigned u; } v; v.f = f;
  unsigned r = v.u + 0x7FFF + ((v.u >> 16) & 1);   // RNE
  return (unsigned short)(r >> 16);
}
__device__ __forceinline__ float bf2f(unsigned short h) {
  union { unsigned u; float f; } v; v.u = ((unsigned)h) << 16; return v.f;
}

// async global -> LDS, 16 B per lane (global_load_lds_dwordx4)
__device__ __forceinline__ void load16_lds(const void* gsrc, void* ldst) {
  __builtin_amdgcn_global_load_lds(
      (const __attribute__((address_space(1))) unsigned int*)gsrc,
      (__attribute__((address_space(3))) unsigned int*)ldst,
      16, 0, 0);
}

// ---------------- weight conversion ----------------
__global__ __launch_bounds__(256) void conv_weights(
    const float* __restrict__ triM, const float* __restrict__ d1w,
    const float* __restrict__ d2w, unsigned short* __restrict__ Mb,
    unsigned short* __restrict__ W1b, unsigned short* __restrict__ W2b) {
  const int idx = blockIdx.x * 256 + threadIdx.x;   // 262144 total
  const int i = idx >> 9, j = idx & 511;
  Mb[idx]  = (j <= i) ? f2bf(triM[idx]) : (unsigned short)0;
  W1b[idx] = f2bf(d1w[idx]);
  W2b[idx] = f2bf(d2w[idx]);
}

// ---------------- ln1 stats: per-batch sum / sumsq ----------------
__global__ __launch_bounds__(256) void ln_stats(const float* __restrict__ x,
                                                float* __restrict__ red) {
  const int b = blockIdx.x;
  const int s = blockIdx.y;                       // 16 splits
  const float4* p = (const float4*)(x + (size_t)b * TC_) + (size_t)s * 4096;
  float s1 = 0.f, s2 = 0.f;
  for (int i = threadIdx.x; i < 4096; i += 256) {
    float4 v = p[i];
    s1 += v.x + v.y + v.z + v.w;
    s2 += v.x * v.x + v.y * v.y + v.z * v.z + v.w * v.w;
  }
#pragma unroll
  for (int o = 32; o; o >>= 1) { s1 += __shfl_down(s1, o, 64); s2 += __shfl_down(s2, o, 64); }
  __shared__ float sm[8];
  const int w = threadIdx.x >> 6, lane = threadIdx.x & 63;
  if (lane == 0) { sm[w * 2] = s1; sm[w * 2 + 1] = s2; }
  __syncthreads();
  if (threadIdx.x == 0) {
    float a = 0.f, c = 0.f;
    for (int i = 0; i < 4; ++i) { a += sm[2 * i]; c += sm[2 * i + 1]; }
    atomicAdd(&red[b * 2], a);
    atomicAdd(&red[b * 2 + 1], c);
  }
}

// ------------- ln1 normalize + transposed bf16 write -------------
// writes XnT[b][c][t] so the mixer GEMM's B-operand is contiguous along K(=t)
__global__ __launch_bounds__(256) void ln1_norm_t(
    const float* __restrict__ x, const float* __restrict__ w,
    const float* __restrict__ bvec, const float* __restrict__ red1,
    unsigned short* __restrict__ XnT) {
  __shared__ unsigned short tile[64][65];
  const int b = blockIdx.z;
  const int t0 = blockIdx.y * 64;
  const int c0 = blockIdx.x * 64;
  const float mu = red1[b * 2] * (1.f / TC_);
  const float rstd = rsqrtf(red1[b * 2 + 1] * (1.f / TC_) - mu * mu + 1e-5f);
  const int tid = threadIdx.x;
  const int r = tid >> 4;            // 0..15
  const int cg = (tid & 15) * 4;     // 0..60
#pragma unroll
  for (int rr = 0; rr < 4; ++rr) {
    const int t = t0 + rr * 16 + r;
    const float4 xv = *(const float4*)&x[((size_t)b * T_ + t) * C_ + c0 + cg];
    const float4 wv = *(const float4*)&w[(size_t)t * C_ + c0 + cg];
    const float4 bv = *(const float4*)&bvec[(size_t)t * C_ + c0 + cg];
    tile[rr * 16 + r][cg + 0] = f2bf((xv.x - mu) * rstd * wv.x + bv.x);
    tile[rr * 16 + r][cg + 1] = f2bf((xv.y - mu) * rstd * wv.y + bv.y);
    tile[rr * 16 + r][cg + 2] = f2bf((xv.z - mu) * rstd * wv.z + bv.z);
    tile[rr * 16 + r][cg + 3] = f2bf((xv.w - mu) * rstd * wv.w + bv.w);
  }
  __syncthreads();
  const int cl = tid >> 2;           // 0..63
  const int tg = (tid & 3) * 16;     // 0,16,32,48
  alignas(16) unsigned short tmp[16];
#pragma unroll
  for (int j = 0; j < 16; ++j) tmp[j] = tile[tg + j][cl];
  unsigned short* o = &XnT[((size_t)b * C_ + c0 + cl) * T_ + t0 + tg];
  *(uint4*)&o[0] = *(const uint4*)&tmp[0];
  *(uint4*)&o[8] = *(const uint4*)&tmp[8];
}

// ---------------- shared GEMM mainloop (2-phase dbuf + swizzle) ----------------
// C[128x128] = A[128xK] @ BT[128xK]^T, A/BT row-major bf16, fp32 acc.
// LDS layout per k-tile: [128 rows][4 chunks of 16B]; physical chunk p of row
// holds logical chunk l = p ^ ((row>>1)&3).  Stage applies the inverse perm on
// the per-lane global address (LDS dest stays linear for global_load_lds);
// fragment reads apply the same XOR -> each 16-lane phase covers all 8 LDS
// 16B-slots exactly twice (conflict-free).
__device__ __forceinline__ void stage_tiles(
    const unsigned short* __restrict__ Ag, const unsigned short* __restrict__ Bg,
    int lda, int ldb, int k0, unsigned short* Abuf, unsigned short* Bbuf, int tid) {
#pragma unroll
  for (int i = 0; i < 2; ++i) {
    const int c = tid + 256 * i;             // chunk id, 16B each
    const int row = c >> 2;
    const int ko = (((c & 3) ^ ((row >> 1) & 3)) * 8);   // swizzled k-offset
    load16_lds(Ag + (size_t)row * lda + k0 + ko, Abuf + c * 8);
    load16_lds(Bg + (size_t)row * ldb + k0 + ko, Bbuf + c * 8);
  }
}

__device__ __forceinline__ void gemm_mainloop(
    const unsigned short* __restrict__ Ag,   // at row i0, ld = lda
    const unsigned short* __restrict__ Bg,   // at row n0 (of BT), ld = ldb
    int lda, int ldb, int ktiles,
    unsigned short* Atile, unsigned short* Btile,   // each 2*4096 shorts
    f32x4 acc[4][4], int tid) {
  const int lane = tid & 63;
  const int w = tid >> 6;
  const int wr = (w >> 1) * 64;
  const int wc = (w & 1) * 64;
  const int m16 = lane & 15;
  const int quad = lane >> 4;
  // (row>>1)&3 depends only on m16 bits 1..2 -> per-lane constant chunk index
  const int ps = (quad ^ ((m16 >> 1) & 3)) * 8;
  unsigned short* Acur = Atile;        unsigned short* Bcur = Btile;
  unsigned short* Anxt = Atile + 4096; unsigned short* Bnxt = Btile + 4096;
  stage_tiles(Ag, Bg, lda, ldb, 0, Acur, Bcur, tid);
  __syncthreads();                             // prologue drain
  for (int kt = 0; kt < ktiles; ++kt) {
    if (kt + 1 < ktiles)                       // prefetch next tile first
      stage_tiles(Ag, Bg, lda, ldb, (kt + 1) * 32, Anxt, Bnxt, tid);
    bf16x8 af[4], bfr[4];
#pragma unroll
    for (int r = 0; r < 4; ++r)
      af[r] = *(const bf16x8*)&Acur[(wr + r * 16 + m16) * 32 + ps];
#pragma unroll
    for (int c = 0; c < 4; ++c)
      bfr[c] = *(const bf16x8*)&Bcur[(wc + c * 16 + m16) * 32 + ps];
#pragma unroll
    for (int r = 0; r < 4; ++r)
#pragma unroll
      for (int c = 0; c < 4; ++c)
        acc[r][c] = __builtin_amdgcn_mfma_f32_16x16x32_bf16(af[r], bfr[c], acc[r][c], 0, 0, 0);
    __syncthreads();   // vmcnt(0)+lgkmcnt(0)+barrier: drains prefetch AFTER compute
    unsigned short* t;
    t = Acur; Acur = Anxt; Anxt = t;
    t = Bcur; Bcur = Bnxt; Bnxt = t;
  }
}

// bijective XCD swizzle for nwg divisible by 8: hw block h -> logical
// (h%8)*(nwg/8) + h/8, so each XCD processes a contiguous logical range.
__device__ __forceinline__ int xcd_swizzle_1024(int bid) {
  return (bid & 7) * 128 + (bid >> 3);
}

// ---------------- mixer GEMM: Z = tril(M)@Xn + tri_b + inputs ----------------
__global__ __launch_bounds__(256) void gemm_mixer(
    const unsigned short* __restrict__ Mb, const unsigned short* __restrict__ XnT,
    const float* __restrict__ trib, const float* __restrict__ inp,
    unsigned short* __restrict__ Z, float* __restrict__ red2) {
  __shared__ __align__(16) unsigned short Atile[8192], Btile[8192];
  const int bid = (blockIdx.z * 4 + blockIdx.y) * 4 + blockIdx.x;  // x fastest
  const int swz = xcd_swizzle_1024(bid);
  const int b = swz >> 4;
  const int i0 = ((swz >> 2) & 3) * 128;
  const int c0 = (swz & 3) * 128;
  f32x4 acc[4][4];
#pragma unroll
  for (int r = 0; r < 4; ++r)
#pragma unroll
    for (int c = 0; c < 4; ++c) acc[r][c] = (f32x4){0.f, 0.f, 0.f, 0.f};
  // tril: rows < i0+128 only need k < i0+128
  gemm_mainloop(Mb + (size_t)i0 * T_, XnT + (size_t)b * TC_ + (size_t)c0 * T_,
                T_, T_, (i0 >> 5) + 4, Atile, Btile, acc, threadIdx.x);
  const int tid = threadIdx.x, lane = tid & 63, w = tid >> 6;
  const int wr = (w >> 1) * 64, wc = (w & 1) * 64, m16 = lane & 15, quad = lane >> 4;
  float s1 = 0.f, s2 = 0.f;
#pragma unroll
  for (int r = 0; r < 4; ++r) {
#pragma unroll
    for (int g = 0; g < 4; ++g) {
      const int i = i0 + wr + r * 16 + quad * 4 + g;
      const float tb = trib[i];
      const float* inrow = &inp[((size_t)b * T_ + i) * C_];
      unsigned short* zrow = &Z[((size_t)b * T_ + i) * C_];
#pragma unroll
      for (int c = 0; c < 4; ++c) {
        const int ch = c0 + wc + c * 16 + m16;
        const float v = acc[r][c][g] + tb + inrow[ch];
        zrow[ch] = f2bf(v);
        s1 += v; s2 += v * v;
      }
    }
  }
#pragma unroll
  for (int o = 32; o; o >>= 1) { s1 += __shfl_down(s1, o, 64); s2 += __shfl_down(s2, o, 64); }
  __shared__ float sm[8];
  if (lane == 0) { sm[w * 2] = s1; sm[w * 2 + 1] = s2; }
  __syncthreads();
  if (tid == 0) {
    float a = 0.f, c2 = 0.f;
    for (int i = 0; i < 4; ++i) { a += sm[2 * i]; c2 += sm[2 * i + 1]; }
    atomicAdd(&red2[b * 2], a);
    atomicAdd(&red2[b * 2 + 1], c2);
  }
}

// ---------------- ln2 normalize ----------------
__global__ __launch_bounds__(256) void ln2_norm(
    const unsigned short* __restrict__ Z, const float* __restrict__ red2,
    const float* __restrict__ w, const float* __restrict__ bvec,
    unsigned short* __restrict__ X2) {
  const size_t e = ((size_t)blockIdx.x * 256 + threadIdx.x) * 8;
  const int b = (int)(e >> 18);
  const int tc = (int)(e & (TC_ - 1));
  const float mu = red2[b * 2] * (1.f / TC_);
  const float rstd = rsqrtf(red2[b * 2 + 1] * (1.f / TC_) - mu * mu + 1e-5f);
  uint4 zp = *(const uint4*)&Z[e];
  const unsigned short* zs = (const unsigned short*)&zp;
  alignas(16) float wv[8], bb[8];
  *(float4*)&wv[0] = *(const float4*)&w[tc];
  *(float4*)&wv[4] = *(const float4*)&w[tc + 4];
  *(float4*)&bb[0] = *(const float4*)&bvec[tc];
  *(float4*)&bb[4] = *(const float4*)&bvec[tc + 4];
  alignas(16) unsigned short o[8];
#pragma unroll
  for (int j = 0; j < 8; ++j)
    o[j] = f2bf((bf2f(zs[j]) - mu) * rstd * wv[j] + bb[j]);
  *(uint4*)&X2[e] = *(const uint4*)&o[0];
}

// ---------------- MLP GEMM 1: H = gelu(X2 @ W1^T + b1) ----------------
__global__ __launch_bounds__(256) void gemm_d1(
    const unsigned short* __restrict__ X2, const unsigned short* __restrict__ W1b,
    const float* __restrict__ d1b, unsigned short* __restrict__ H) {
  __shared__ __align__(16) unsigned short Atile[8192], Btile[8192];
  const int bid = blockIdx.y * 4 + blockIdx.x;
  const int swz = xcd_swizzle_1024(bid);
  const int i0 = (swz >> 2) * 128;
  const int n0 = (swz & 3) * 128;
  f32x4 acc[4][4];
#pragma unroll
  for (int r = 0; r < 4; ++r)
#pragma unroll
    for (int c = 0; c < 4; ++c) acc[r][c] = (f32x4){0.f, 0.f, 0.f, 0.f};
  gemm_mainloop(X2 + (size_t)i0 * C_, W1b + (size_t)n0 * C_, C_, C_, 16,
                Atile, Btile, acc, threadIdx.x);
  const int tid = threadIdx.x, lane = tid & 63, w = tid >> 6;
  const int wr = (w >> 1) * 64, wc = (w & 1) * 64, m16 = lane & 15, quad = lane >> 4;
#pragma unroll
  for (int r = 0; r < 4; ++r) {
#pragma unroll
    for (int g = 0; g < 4; ++g) {
      const int row = i0 + wr + r * 16 + quad * 4 + g;
#pragma unroll
      for (int c = 0; c < 4; ++c) {
        const int n = n0 + wc + c * 16 + m16;
        const float v = acc[r][c][g] + d1b[n];
        const float gl = 0.5f * v * (1.0f + erff(v * 0.70710678118654752f));
        H[(size_t)row * C_ + n] = f2bf(gl);
      }
    }
  }
}

// ---------------- MLP GEMM 2: out = X2 + H @ W2^T + b2 ----------------
__global__ __launch_bounds__(256) void gemm_d2(
    const unsigned short* __restrict__ H, const unsigned short* __restrict__ W2b,
    const float* __restrict__ d2b, const unsigned short* __restrict__ X2,
    float* __restrict__ out) {
  __shared__ __align__(16) unsigned short Atile[8192], Btile[8192];
  const int bid = blockIdx.y * 4 + blockIdx.x;
  const int swz = xcd_swizzle_1024(bid);
  const int i0 = (swz >> 2) * 128;
  const int n0 = (swz & 3) * 128;
  f32x4 acc[4][4];
#pragma unroll
  for (int r = 0; r < 4; ++r)
#pragma unroll
    for (int c = 0; c < 4; ++c) acc[r][c] = (f32x4){0.f, 0.f, 0.f, 0.f};
  gemm_mainloop(H + (size_t)i0 * C_, W2b + (size_t)n0 * C_, C_, C_, 16,
                Atile, Btile, acc, threadIdx.x);
  const int tid = threadIdx.x, lane = tid & 63, w = tid >> 6;
  const int wr = (w >> 1) * 64, wc = (w & 1) * 64, m16 = lane & 15, quad = lane >> 4;
#pragma unroll
  for (int r = 0; r < 4; ++r) {
#pragma unroll
    for (int g = 0; g < 4; ++g) {
      const int row = i0 + wr + r * 16 + quad * 4 + g;
#pragma unroll
      for (int c = 0; c < 4; ++c) {
        const int n = n0 + wc + c * 16 + m16;
        out[(size_t)row * C_ + n] = acc[r][c][g] + d2b[n] + bf2f(X2[(size_t)row * C_ + n]);
      }
    }
  }
}

extern "C" void kernel_launch(void* const* d_in, const int* in_sizes, int n_in,
                              void* d_out, int out_size, void* d_ws, size_t ws_size,
                              hipStream_t stream) {
  const float* inp  = (const float*)d_in[0];
  const float* ln1w = (const float*)d_in[1];
  const float* ln1b = (const float*)d_in[2];
  const float* ln2w = (const float*)d_in[3];
  const float* ln2b = (const float*)d_in[4];
  const float* triM = (const float*)d_in[5];
  const float* trib = (const float*)d_in[6];
  const float* d1w  = (const float*)d_in[7];
  const float* d1b  = (const float*)d_in[8];
  const float* d2w  = (const float*)d_in[9];
  const float* d2b  = (const float*)d_in[10];
  float* out = (float*)d_out;

  char* ws = (char*)d_ws;
  float* red1 = (float*)ws;                         // 64*2 floats
  float* red2 = (float*)(ws + 512);                 // 64*2 floats
  unsigned short* Mb  = (unsigned short*)(ws + 1024);
  unsigned short* W1b = Mb + TC_;
  unsigned short* W2b = W1b + TC_;
  unsigned short* XnT = W2b + TC_;                  // [B][C][T] bf16
  unsigned short* Z   = XnT + (size_t)B_ * TC_;     // [B][T][C] bf16
  unsigned short* X2  = Z + (size_t)B_ * TC_;       // [B][T][C] bf16
  unsigned short* H   = X2 + (size_t)B_ * TC_;      // [B*T][C] bf16

  hipMemsetAsync(ws, 0, 1024, stream);
  conv_weights<<<1024, 256, 0, stream>>>(triM, d1w, d2w, Mb, W1b, W2b);
  ln_stats<<<dim3(B_, 16), 256, 0, stream>>>(inp, red1);
  ln1_norm_t<<<dim3(8, 8, B_), 256, 0, stream>>>(inp, ln1w, ln1b, red1, XnT);
  gemm_mixer<<<dim3(4, 4, B_), 256, 0, stream>>>(Mb, XnT, trib, inp, Z, red2);
  ln2_norm<<<8192, 256, 0, stream>>>(Z, red2, ln2w, ln2b, X2);
  gemm_d1<<<dim3(4, 256), 256, 0, stream>>>(X2, W1b, d1b, H);
  gemm_d2<<<dim3(4, 256), 256, 0, stream>>>(H, W2b, d2b, X2, out);
}